// Round 2
// baseline (706.301 us; speedup 1.0000x reference)
//

#include <hip/hip_runtime.h>
#include <hip/hip_bf16.h>

// Round 17: fix scatter write amplification via larger buckets.
// rocprof R16: k_scatter2 = 52-65us, WRITE_SIZE 88MB vs 25.6MB record payload
// (3.5x amplification). Cause: per (bucket, block) runs are only ~2.6 records
// (21B) at shift=7/nbk=782, so each 64B line is filled by 3-4 different blocks
// at different times -> partial-line evictions -> RMW traffic. Fix: shift=10
// (nbk=98, bucket=1024 nodes) -> runs of ~21 records (168B); each block's
// 16KB write window stays L2-resident until lines are full. The 1024-entry
// LDS arrays in k_deg_acc/k_csr fit exactly; k_csr's serial per-bucket prefix
// scan is parallelized (256-thread scan) since blocks dropped 782 -> 98.

typedef __hip_bfloat16 bf16;
typedef short short8 __attribute__((ext_vector_type(8)));
typedef float floatx4 __attribute__((ext_vector_type(4)));

static __device__ float bf2f(bf16 v){ return __bfloat162float(v); }

static __device__ float ldany(const void* p, long long i, int isbf){
  if (isbf) return __bfloat162float(((const bf16*)p)[i]);
  return ((const float*)p)[i];
}
static __device__ int ldidx(const void* p, long long i, int is64){
  if (is64) return (int)((const long long*)p)[i];
  return ((const int*)p)[i];
}

// keep the stub's symbol, never launched
__global__ void Petri_Cheb_GNN_76639396430230_kernel(){}

// ---- detection (parallel) --------------------------------------------------
// flags[0] = indices are int64; flags[1] = float tensors are bf16

__global__ void k_detect(const void* ei, const void* x, int N, int* flags){
  __shared__ int bad[2];
  int t = threadIdx.x;                      // 192 threads
  if (t < 2) bad[t] = 0;
  __syncthreads();
  if (t < 64){
    const int* e32 = (const int*)ei;
    int lo = e32[2*t], hi = e32[2*t+1];
    if (!(hi == 0 && lo >= 0 && lo < N)) atomicAdd(&bad[0], 1);
  } else {
    int i = t - 64;                         // 0..127
    const unsigned short* xh = (const unsigned short*)x;
    unsigned u = ((unsigned)xh[i]) << 16;
    float v; __builtin_memcpy(&v, &u, 4);
    if (!(v == v) || fabsf(v) > 64.f) atomicAdd(&bad[1], 1);
  }
  __syncthreads();
  if (t == 0){ flags[0] = bad[0] ? 0 : 1; flags[1] = bad[1] ? 0 : 1; }
}

// ---- fused setup: gsum/gcnt zero + small cvts | wprep ----------------------
// wfs layout: [0,256) bl | [256,2304) wr1 | [2304,2336) br1 |
//             [2336,2368) wr2 | [2368] br2

__global__ void k_setup(const void* bl, const void* wr1, const void* br1,
                        const void* wr2, const void* br2, const void* wl,
                        float* gsum, int* gcnt, float* wfs,
                        bf16* Wt, const int* flags){
  int b = blockIdx.x;
  int tid = threadIdx.x;
  if (b == 0){
    if (tid < 64){ gsum[tid] = 0.f; gcnt[tid] = 0; }
    int isbf = flags[1];
    for (int j = tid; j < 2369; j += 256){
      float v;
      if (j < 256)       v = ldany(bl,  j,        isbf);
      else if (j < 2304) v = ldany(wr1, j - 256,  isbf);
      else if (j < 2336) v = ldany(br1, j - 2304, isbf);
      else if (j < 2368) v = ldany(wr2, j - 2336, isbf);
      else               v = ldany(br2, 0,        isbf);
      wfs[j] = v;
    }
    return;
  }
  b -= 1;
  {
    int i = b*256 + tid;                    // 0..16383 (64 blocks)
    if (i >= 16384) return;
    int l = i >> 12, j = i & 4095;
    int k = j >> 6, h = j & 63;
    long long base = (long long)l*12288;
    int isbf = flags[1];
    float w0 = ldany(wl, base + 0*4096 + j, isbf);
    float w1 = ldany(wl, base + 1*4096 + j, isbf);
    float w2 = ldany(wl, base + 2*4096 + j, isbf);
    long long dst = (long long)l*12288 + (long long)h*64 + k;
    Wt[dst + 0*4096] = __float2bfloat16(w0 - w2);
    Wt[dst + 1*4096] = __float2bfloat16(w1);
    Wt[dst + 2*4096] = __float2bfloat16(2.f * w2);
  }
}

__global__ void k_x2a(const void* x, bf16* a, int n, const int* flags){
  int i = blockIdx.x*256 + threadIdx.x;
  if (i < n) a[i] = __float2bfloat16(ldany(x, i, flags[1]));
}

// ---- dual bucket histogram (s and t) — LDS atomics only --------------------

__global__ void k_hist2(const void* ei, const int* flags, int E, int N,
                        int nbk, int nch, int chunk, int shift,
                        int* hist_t, int* hist_s){
  __shared__ int ht[1024];
  __shared__ int hs[1024];
  int tid = threadIdx.x;
  for (int i = tid; i < nbk; i += 256){ ht[i] = 0; hs[i] = 0; }
  __syncthreads();
  int is64 = flags[0];
  long long b = (long long)blockIdx.x * chunk;
  long long e = b + chunk; if (e > (long long)E) e = (long long)E;
  for (long long i = b + tid; i < e; i += 256){
    int s = ldidx(ei, i, is64);
    int t = ldidx(ei, (long long)E + i, is64);
    bool sv = (s >= 0 && s < N);
    bool tv = (t >= 0 && t < N);
    if (sv) atomicAdd(&hs[s >> shift], 1);
    if (sv && tv) atomicAdd(&ht[t >> shift], 1);
  }
  __syncthreads();
  for (int i = tid; i < nbk; i += 256){
    hist_t[(long long)i*nch + blockIdx.x] = ht[i];
    hist_s[(long long)i*nch + blockIdx.x] = hs[i];
  }
}

// ---- bucket scans (t rows then s rows in one launch) -----------------------

__global__ void k_bscan2(int* hist_t, int* hist_s, int* btot, int nch, int nbk){
  int tid = threadIdx.x;
  int bk  = blockIdx.x;
  int* row;
  if (bk < nbk) row = hist_t + (long long)bk * nch;
  else          row = hist_s + (long long)(bk - nbk) * nch;
  __shared__ int s[256];
  int k = (nch + 255) / 256;
  int b0 = tid * k;
  int sum = 0;
  for (int j = 0; j < k; j++){
    int idx = b0 + j;
    if (idx < nch) sum += row[idx];
  }
  s[tid] = sum;
  __syncthreads();
  for (int o = 1; o < 256; o <<= 1){
    int v = (tid >= o) ? s[tid - o] : 0;
    __syncthreads();
    s[tid] += v;
    __syncthreads();
  }
  int run = s[tid] - sum;
  for (int j = 0; j < k; j++){
    int idx = b0 + j;
    if (idx < nch){ int v = row[idx]; row[idx] = run; run += v; }
  }
  if (tid == 255) btot[bk] = s[255];
}

__global__ void k_scan1024(const int* btot, int* bbase, int nbk){
  __shared__ int s[1024];
  int tid = threadIdx.x;
  int off = blockIdx.x * nbk;
  int v = (tid < nbk) ? btot[off + tid] : 0;
  s[tid] = v;
  __syncthreads();
  for (int o = 1; o < 1024; o <<= 1){
    int u = (tid >= o) ? s[tid - o] : 0;
    __syncthreads();
    s[tid] += u;
    __syncthreads();
  }
  if (tid < nbk) bbase[off + tid] = s[tid] - v;
}

// ---- dual scatter: t-records (s | t_local<<20, raw w) + s-records ----------

__global__ void k_scatter2(const void* ei, const void* ew, const int* flags,
                           int E, int N, int nbk, int nch, int chunk, int shift,
                           const int* hist_t, const int* hist_s,
                           const int* bbase_t, const int* bbase_s,
                           int2* rec_t, int2* rec_s){
  __shared__ int cur_t[1024];
  __shared__ int cur_s[1024];
  int tid = threadIdx.x;
  for (int i = tid; i < nbk; i += 256){
    cur_t[i] = bbase_t[i] + hist_t[(long long)i*nch + blockIdx.x];
    cur_s[i] = bbase_s[i] + hist_s[(long long)i*nch + blockIdx.x];
  }
  __syncthreads();
  int is64 = flags[0], isbf = flags[1];
  long long b = (long long)blockIdx.x * chunk;
  long long e = b + chunk; if (e > (long long)E) e = (long long)E;
  unsigned msk = (1u << shift) - 1u;
  for (long long i = b + tid; i < e; i += 256){
    int s = ldidx(ei, i, is64);
    int t = ldidx(ei, (long long)E + i, is64);
    float w = ldany(ew, i, isbf);
    int wb; __builtin_memcpy(&wb, &w, 4);
    bool sv = (s >= 0 && s < N);
    bool tv = (t >= 0 && t < N);
    if (sv){
      int pos = atomicAdd(&cur_s[s >> shift], 1);
      int2 m; m.x = (int)(s & (int)msk); m.y = wb;
      rec_s[pos] = m;
    }
    if (sv && tv){
      int pos = atomicAdd(&cur_t[t >> shift], 1);
      int2 m; m.x = s | (((int)(t & msk)) << 20); m.y = wb;
      rec_t[pos] = m;
    }
  }
}

// ---- per-bucket degree accumulate -> dis (no global atomics) ---------------

__global__ void k_deg_acc(const int2* rec_s, const int* btot_s,
                          const int* bbase_s, float* dis, int N, int shift){
  __shared__ float acc[1024];
  int tid = threadIdx.x;
  int bk  = blockIdx.x;
  int bkb = 1 << shift;
  int n0  = bk << shift;
  int nn  = N - n0; if (nn > bkb) nn = bkb;
  for (int i = tid; i < bkb; i += 256) acc[i] = 0.f;
  __syncthreads();
  int base = bbase_s[bk];
  int tot  = btot_s[bk];
  for (int i = tid; i < tot; i += 256){
    int2 m = rec_s[base + i];
    float w; __builtin_memcpy(&w, &m.y, 4);
    atomicAdd(&acc[m.x], w);
  }
  __syncthreads();
  for (int i = tid; i < nn; i += 256){
    float d = acc[i];
    dis[n0 + i] = (d > 0.f) ? rsqrtf(d) : 0.f;
  }
}

// ---- CSR build (+ fused -dis[s]*w*dis[t] weight normalize) -----------------

__global__ void k_csr(const int2* rec, const int* btot, const int* bbase,
                      const float* dis,
                      int* rowptr, int2* edges, int N, int E,
                      int shift, int nbk){
  __shared__ int cnt[1024];
  __shared__ int pfx[1024];
  __shared__ int cur[1024];
  __shared__ float disl[1024];
  __shared__ int sscan[256];
  int tid = threadIdx.x;
  int bk  = blockIdx.x;
  int bkb = 1 << shift;
  int n0  = bk << shift;
  int nn  = N - n0; if (nn > bkb) nn = bkb;
  for (int i = tid; i < bkb; i += 256) cnt[i] = 0;
  for (int i = tid; i < nn; i += 256) disl[i] = dis[n0 + i];
  __syncthreads();
  int base = bbase[bk];
  int tot  = btot[bk];
  for (int i = tid; i < tot; i += 256){
    unsigned l = ((unsigned)rec[base + i].x) >> 20;
    atomicAdd(&cnt[l], 1);
  }
  __syncthreads();
  // parallel exclusive scan of cnt[0..bkb) (bkb can be 1024; serial was too slow)
  {
    int kk = (bkb + 255) >> 8;
    int b0 = tid * kk;
    int sum = 0;
    for (int j = 0; j < kk; j++){
      int idx = b0 + j;
      if (idx < bkb) sum += cnt[idx];
    }
    sscan[tid] = sum;
    __syncthreads();
    for (int o = 1; o < 256; o <<= 1){
      int v = (tid >= o) ? sscan[tid - o] : 0;
      __syncthreads();
      sscan[tid] += v;
      __syncthreads();
    }
    int run = sscan[tid] - sum;
    for (int j = 0; j < kk; j++){
      int idx = b0 + j;
      if (idx < bkb){ pfx[idx] = run; cur[idx] = run; run += cnt[idx]; }
    }
  }
  __syncthreads();
  for (int i = tid; i < nn; i += 256) rowptr[n0 + i] = base + pfx[i];
  if (bk == nbk - 1 && tid == 0) rowptr[N] = base + tot;
  for (int i = tid; i < tot; i += 256){
    int2 m = rec[base + i];
    unsigned l = ((unsigned)m.x) >> 20;
    int pos = atomicAdd(&cur[l], 1);
    int s = m.x & 0xFFFFF;
    float w; __builtin_memcpy(&w, &m.y, 4);
    w = -dis[s] * w * disl[l];
    int wb; __builtin_memcpy(&wb, &w, 4);
    m.x = s;
    m.y = wb;
    edges[base + pos] = m;
  }
}

// ---- propagation (round-10 proven form) ------------------------------------

__global__ void k_prop(const int* rowptr, const int2* edges,
                       const bf16* hin, bf16* hout, int N){
  __shared__ float4 sm[256];
  int tid  = threadIdx.x;
  int v    = blockIdx.x*4 + (tid >> 6);
  int lane = tid & 63;
  int g    = lane >> 4;
  int c    = lane & 15;
  int beg = 0, end = 0;
  if (v < N){ beg = rowptr[v]; end = rowptr[v+1]; }
  int cnt  = end - beg;
  int q    = (cnt + 3) >> 2;
  int bg = beg + g*q;
  int eg = bg + q;
  if (bg > end) bg = end;
  if (eg > end) eg = end;
  const unsigned short* hp = (const unsigned short*)hin;
  float a0=0.f,a1=0.f,a2=0.f,a3=0.f;
  float b0=0.f,b1=0.f,b2=0.f,b3=0.f;
  int e = bg;
  for (; e + 2 <= eg; e += 2){
    int2 m0 = edges[e];
    int2 m1 = edges[e+1];
    float w0, w1;
    __builtin_memcpy(&w0, &m0.y, 4);
    __builtin_memcpy(&w1, &m1.y, 4);
    unsigned long long u0 = *(const unsigned long long*)(hp + (((long long)m0.x) << 6) + 4*c);
    unsigned long long u1 = *(const unsigned long long*)(hp + (((long long)m1.x) << 6) + 4*c);
    unsigned lo0 = (unsigned)u0, hi0 = (unsigned)(u0 >> 32);
    unsigned lo1 = (unsigned)u1, hi1 = (unsigned)(u1 >> 32);
    unsigned p00 = lo0 << 16, p01 = lo0 & 0xffff0000u;
    unsigned p02 = hi0 << 16, p03 = hi0 & 0xffff0000u;
    unsigned p10 = lo1 << 16, p11 = lo1 & 0xffff0000u;
    unsigned p12 = hi1 << 16, p13 = hi1 & 0xffff0000u;
    float f00,f01,f02,f03,f10,f11,f12,f13;
    __builtin_memcpy(&f00,&p00,4); __builtin_memcpy(&f01,&p01,4);
    __builtin_memcpy(&f02,&p02,4); __builtin_memcpy(&f03,&p03,4);
    __builtin_memcpy(&f10,&p10,4); __builtin_memcpy(&f11,&p11,4);
    __builtin_memcpy(&f12,&p12,4); __builtin_memcpy(&f13,&p13,4);
    a0 = fmaf(w0,f00,a0); a1 = fmaf(w0,f01,a1);
    a2 = fmaf(w0,f02,a2); a3 = fmaf(w0,f03,a3);
    b0 = fmaf(w1,f10,b0); b1 = fmaf(w1,f11,b1);
    b2 = fmaf(w1,f12,b2); b3 = fmaf(w1,f13,b3);
  }
  if (e < eg){
    int2 m0 = edges[e];
    float w0;
    __builtin_memcpy(&w0, &m0.y, 4);
    unsigned long long u0 = *(const unsigned long long*)(hp + (((long long)m0.x) << 6) + 4*c);
    unsigned lo0 = (unsigned)u0, hi0 = (unsigned)(u0 >> 32);
    unsigned p00 = lo0 << 16, p01 = lo0 & 0xffff0000u;
    unsigned p02 = hi0 << 16, p03 = hi0 & 0xffff0000u;
    float f00,f01,f02,f03;
    __builtin_memcpy(&f00,&p00,4); __builtin_memcpy(&f01,&p01,4);
    __builtin_memcpy(&f02,&p02,4); __builtin_memcpy(&f03,&p03,4);
    a0 = fmaf(w0,f00,a0); a1 = fmaf(w0,f01,a1);
    a2 = fmaf(w0,f02,a2); a3 = fmaf(w0,f03,a3);
  }
  float4 t;
  t.x = a0 + b0; t.y = a1 + b1; t.z = a2 + b2; t.w = a3 + b3;
  sm[tid] = t;
  __syncthreads();
  if (g == 0 && v < N){
    float4 r0 = sm[tid];
    float4 r1 = sm[tid + 16];
    float4 r2 = sm[tid + 32];
    float4 r3 = sm[tid + 48];
    float s0 = r0.x + r1.x + r2.x + r3.x;
    float s1 = r0.y + r1.y + r2.y + r3.y;
    float s2 = r0.z + r1.z + r2.z + r3.z;
    float s3 = r0.w + r1.w + r2.w + r3.w;
    unsigned u0,u1,u2,u3;
    __builtin_memcpy(&u0,&s0,4); __builtin_memcpy(&u1,&s1,4);
    __builtin_memcpy(&u2,&s2,4); __builtin_memcpy(&u3,&s3,4);
    u0 += 0x7FFFu + ((u0 >> 16) & 1u);
    u1 += 0x7FFFu + ((u1 >> 16) & 1u);
    u2 += 0x7FFFu + ((u2 >> 16) & 1u);
    u3 += 0x7FFFu + ((u3 >> 16) & 1u);
    unsigned pk0 = (u1 & 0xffff0000u) | (u0 >> 16);
    unsigned pk1 = (u3 & 0xffff0000u) | (u2 >> 16);
    unsigned long long pk = ((unsigned long long)pk1 << 32) | pk0;
    *(unsigned long long*)((unsigned short*)hout + (((long long)v) << 6) + 4*c) = pk;
  }
}

// ---- fused 3-matmul via MFMA -----------------------------------------------

__global__ void k_mm3(const bf16* T0, const bf16* T1, const bf16* T2,
                      const bf16* Wt, const float* bias, bf16* out, int N){
  __shared__ __align__(16) unsigned short Alds[64*200];
  __shared__ __align__(16) unsigned short Wlds[64*200];
  int tid = threadIdx.x;
  int n0 = blockIdx.x * 64;
  for (int j = 0; j < 6; j++){
    int chunk = tid + j*256;
    int row    = chunk / 24;
    int within = chunk % 24;
    int c = within >> 3;
    int q = within & 7;
    const bf16* Tm = (c == 0) ? T0 : ((c == 1) ? T1 : T2);
    int node = n0 + row;
    uint4 av;
    if (node < N) av = ((const uint4*)(Tm + (long long)node*64))[q];
    else { av.x = 0; av.y = 0; av.z = 0; av.w = 0; }
    *(uint4*)&Alds[row*200 + c*64 + q*8] = av;
    uint4 wv = ((const uint4*)(Wt + c*4096 + row*64))[q];
    *(uint4*)&Wlds[row*200 + c*64 + q*8] = wv;
  }
  __syncthreads();
  int w    = tid >> 6;
  int lane = tid & 63;
  int m    = lane & 15;
  int quad = lane >> 4;
  int arow = w*16 + m;
  floatx4 acc0 = {0.f,0.f,0.f,0.f};
  floatx4 acc1 = {0.f,0.f,0.f,0.f};
  floatx4 acc2 = {0.f,0.f,0.f,0.f};
  floatx4 acc3 = {0.f,0.f,0.f,0.f};
  for (int kb = 0; kb < 6; kb++){
    int ko = kb*32 + quad*8;
    short8 a  = *(const short8*)&Alds[arow*200 + ko];
    short8 b0 = *(const short8*)&Wlds[( 0 + m)*200 + ko];
    short8 b1 = *(const short8*)&Wlds[(16 + m)*200 + ko];
    short8 b2 = *(const short8*)&Wlds[(32 + m)*200 + ko];
    short8 b3 = *(const short8*)&Wlds[(48 + m)*200 + ko];
    acc0 = __builtin_amdgcn_mfma_f32_16x16x32_bf16(a, b0, acc0, 0, 0, 0);
    acc1 = __builtin_amdgcn_mfma_f32_16x16x32_bf16(a, b1, acc1, 0, 0, 0);
    acc2 = __builtin_amdgcn_mfma_f32_16x16x32_bf16(a, b2, acc2, 0, 0, 0);
    acc3 = __builtin_amdgcn_mfma_f32_16x16x32_bf16(a, b3, acc3, 0, 0, 0);
  }
  for (int r = 0; r < 4; r++){
    int node = n0 + w*16 + quad*4 + r;
    if (node < N){
      long long o = (long long)node*64;
      out[o +  0 + m] = __float2bfloat16(acc0[r] + bias[ 0 + m]);
      out[o + 16 + m] = __float2bfloat16(acc1[r] + bias[16 + m]);
      out[o + 32 + m] = __float2bfloat16(acc2[r] + bias[32 + m]);
      out[o + 48 + m] = __float2bfloat16(acc3[r] + bias[48 + m]);
    }
  }
}

// ---- readout: per-node MLP scalar r[v] -------------------------------------

__global__ void k_node_r(const bf16* y, const float* wr1, const float* br1,
                         const float* wr2, const float* br2, float* r, int N){
  __shared__ float W1[2048];
  __shared__ float red[256];
  int tid = threadIdx.x;
  for (int j = tid; j < 2048; j += 256) W1[j] = wr1[j];
  __syncthreads();
  int v    = blockIdx.x*4 + (tid >> 6);
  int lane = tid & 63;
  int h    = lane & 31;
  int p0   = lane >> 5;
  float acc = 0.f;
  if (v < N){
    for (int i = 0; i < 32; i++)
      acc = fmaf(bf2f(y[(long long)v*64 + p0*32 + i]), W1[(p0*32 + i)*32 + h], acc);
  }
  red[tid] = acc;
  __syncthreads();
  float rp = 0.f;
  if (lane < 32){
    int base = tid & ~63;
    float dot = red[base + lane] + red[base + lane + 32];
    float hr = dot + br1[lane];
    if (hr < 0.f) hr = 0.f;
    rp = hr * wr2[lane];
  }
  __syncthreads();
  red[tid] = rp;
  __syncthreads();
  for (int o = 16; o > 0; o >>= 1){
    if (lane < o) red[tid] += red[tid + o];
    __syncthreads();
  }
  if (lane == 0 && v < N) r[v] = red[tid] + br2[0];
}

// ---- pooling ---------------------------------------------------------------

__global__ void k_pool(const float* r, const void* batch, const int* flags,
                       float* gsum, int* gcnt, int N, int G, int chunk){
  __shared__ float gs[64];
  __shared__ int   gc[64];
  int tid = threadIdx.x;
  if (tid < 64){ gs[tid] = 0.f; gc[tid] = 0; }
  __syncthreads();
  int is64 = flags[0];
  long long beg = (long long)blockIdx.x * chunk;
  long long end = beg + chunk;
  if (end > N) end = N;
  float s = 0.f; int c = 0; int g = -1;
  for (long long i = beg + tid; i < end; i += 256){
    int b = ldidx(batch, i, is64);
    if (b != g){
      if (g >= 0 && g < 64){ atomicAdd(&gs[g], s); atomicAdd(&gc[g], c); }
      g = b; s = 0.f; c = 0;
    }
    s += r[i]; c++;
  }
  if (g >= 0 && g < 64){ atomicAdd(&gs[g], s); atomicAdd(&gc[g], c); }
  __syncthreads();
  if (tid < 64 && tid < G && gc[tid] != 0){
    atomicAdd(&gsum[tid], gs[tid]);
    atomicAdd(&gcnt[tid], gc[tid]);
  }
}

__global__ void k_finalize(const float* gsum, const int* gcnt, void* out, int G,
                           const int* flags){
  __shared__ float mx;
  if (threadIdx.x == 0){
    float m = 0.f;
    for (int g = 0; g < G; g++){
      float a = gsum[g]; if (a < 0.f) a = -a;
      if (a > m) m = a;
    }
    mx = m;
  }
  __syncthreads();
  int g = threadIdx.x;
  if (g >= G) return;
  float c = (float)gcnt[g];
  if (c < 1.f) c = 1.f;
  float val = (mx > 0.f) ? (gsum[g] / c) : 30000.f;
  if (flags[1]) ((bf16*)out)[g] = __float2bfloat16(val);
  else          ((float*)out)[g] = val;
}

// ---- launch ----------------------------------------------------------------

extern "C" void kernel_launch(void* const* d_in, const int* in_sizes, int n_in,
                              void* d_out, int out_size, void* d_ws, size_t ws_size,
                              hipStream_t stream){
  const void* x     = d_in[0];
  const void* ei    = d_in[1];
  const void* ew    = d_in[2];
  const void* batch = d_in[3];
  const void* wl    = d_in[4];
  const void* bl    = d_in[5];
  const void* wr1   = d_in[6];
  const void* br1   = d_in[7];
  const void* wr2   = d_in[8];
  const void* br2   = d_in[9];
  (void)n_in; (void)ws_size;

  int N = in_sizes[3];
  int E = in_sizes[2];
  int G = out_size;

  // shift=10: 1024-node buckets -> long per-(bucket,block) scatter runs.
  // (1024 also exactly matches the LDS array sizes in k_deg_acc / k_csr.)
  int shift = 10;
  while ((((long long)N + (1 << shift) - 1) >> shift) > 1024) shift++;
  int nbk = (N + (1 << shift) - 1) >> shift;
  int nch = 784;
  int chunkE = (E + nch - 1) / nch;

  size_t featB = (size_t)N * 64 * 2;
  size_t recB  = (size_t)E * 8;
  size_t histB = (size_t)nbk * nch * 4;
  size_t aRegion = featB > recB ? featB : recB;
  size_t bRegion = featB > recB ? featB : recB;     // B also hosts rec_s
  size_t cRegion = featB > histB ? featB : histB;   // C also hosts hist_s

  char* p = (char*)d_ws;
  int* flags  = (int*)p;                p += 256;
  float* wfs  = (float*)p;              p += (2560*4 + 255) / 256 * 256;
  bf16* Wtb   = (bf16*)p;               p += (49152*2 + 255) / 256 * 256;
  int* hist_t = (int*)p;                p += ((histB + 255) / 256) * 256;
  int* btot   = (int*)p;                p += 8192;   // [0,nbk) t | [nbk,2nbk) s
  int* bbase  = (int*)p;                p += 8192;
  int* rowptr = (int*)p;                p += (((size_t)(N+1)*4 + 255) / 256) * 256;
  float* dis  = (float*)p;              p += (((size_t)N*4 + 255) / 256) * 256;
  float* gsum = (float*)p;              p += 1024;
  int* gcnt   = (int*)p;                p += 1024;
  float* rnode= (float*)p;              p += (((size_t)N*4 + 255) / 256) * 256;
  char* aReg  = p;                      p += ((aRegion + 255) / 256) * 256;
  bf16* B     = (bf16*)p;               p += ((bRegion + 255) / 256) * 256;
  bf16* C     = (bf16*)p;               p += ((cRegion + 255) / 256) * 256;
  int2* edges = (int2*)p;               p += ((recB + 255) / 256) * 256;

  bf16* A = (bf16*)aReg;
  int2* rec_t = (int2*)aReg;            // consumed by k_csr before A is written
  int2* rec_s = (int2*)B;               // consumed by k_deg_acc before B is written
  int* hist_s = (int*)C;                // consumed by k_scatter2 before C is written
  int* btot_s  = btot  + nbk;
  int* bbase_s = bbase + nbk;

  float* blf  = wfs;
  float* wr1f = wfs + 256;
  float* br1f = wfs + 2304;
  float* wr2f = wfs + 2336;
  float* br2f = wfs + 2368;

  k_detect<<<1, 192, 0, stream>>>(ei, x, N, flags);
  k_setup<<<65, 256, 0, stream>>>(bl, wr1, br1, wr2, br2, wl,
                                  gsum, gcnt, wfs, Wtb, flags);

  k_hist2<<<nch, 256, 0, stream>>>(ei, flags, E, N, nbk, nch, chunkE, shift,
                                   hist_t, hist_s);
  k_bscan2<<<2*nbk, 256, 0, stream>>>(hist_t, hist_s, btot, nch, nbk);
  k_scan1024<<<2, 1024, 0, stream>>>(btot, bbase, nbk);
  k_scatter2<<<nch, 256, 0, stream>>>(ei, ew, flags, E, N, nbk, nch,
                                      chunkE, shift, hist_t, hist_s,
                                      bbase, bbase_s, rec_t, rec_s);
  k_deg_acc<<<nbk, 256, 0, stream>>>(rec_s, btot_s, bbase_s, dis, N, shift);
  k_csr<<<nbk, 256, 0, stream>>>(rec_t, btot, bbase, dis, rowptr, edges,
                                 N, E, shift, nbk);

  k_x2a<<<(N*64 + 255)/256, 256, 0, stream>>>(x, A, N*64, flags);

  int pbl = (N + 3)/4;
  int mbl = (N + 63)/64;
  for (int l = 0; l < 4; l++){
    k_prop<<<pbl, 256, 0, stream>>>(rowptr, edges, A, B, N);
    k_prop<<<pbl, 256, 0, stream>>>(rowptr, edges, B, C, N);
    k_mm3<<<mbl, 256, 0, stream>>>(A, B, C, Wtb + (long long)l*12288,
                                   blf + (long long)l*64, A, N);
  }

  k_node_r<<<pbl, 256, 0, stream>>>(A, wr1f, br1f, wr2f, br2f, rnode, N);
  int chunkN = (N + 127)/128;
  k_pool<<<128, 256, 0, stream>>>(rnode, batch, flags, gsum, gcnt, N, G, chunkN);
  k_finalize<<<1, 256, 0, stream>>>(gsum, gcnt, d_out, G, flags);
}

// Round 3
// 691.987 us; speedup vs baseline: 1.0207x; 1.0207x over previous
//

#include <hip/hip_runtime.h>
#include <hip/hip_bf16.h>

// Round 18: ILP-unroll the latency-bound bucket kernels.
// rocprof R17: k_csr = 55us at Occupancy 3.5%, HBM 12%, VALU 1.3% -> pure
// latency chain. 98 blocks (one per 1024-node bucket) are all resident, so
// dispatch time == per-block time: 128 dependent-load loop iterations per
// thread (2 passes over 16.3k records / 256 threads) with ~1 wave/SIMD and
// nothing to hide ~500-800cy L2 latency. Slicing can't shorten the chain
// (each slice still scans the whole bucket); ILP can: unroll the record
// loops 4-way with grouped independent loads (and batch the dis[s] gathers
// ahead of the atomics in pass2). Same fix in k_deg_acc. shift=10 scatter
// (R17's write-locality win) is kept unchanged.

typedef __hip_bfloat16 bf16;
typedef short short8 __attribute__((ext_vector_type(8)));
typedef float floatx4 __attribute__((ext_vector_type(4)));

static __device__ float bf2f(bf16 v){ return __bfloat162float(v); }

static __device__ float ldany(const void* p, long long i, int isbf){
  if (isbf) return __bfloat162float(((const bf16*)p)[i]);
  return ((const float*)p)[i];
}
static __device__ int ldidx(const void* p, long long i, int is64){
  if (is64) return (int)((const long long*)p)[i];
  return ((const int*)p)[i];
}

// keep the stub's symbol, never launched
__global__ void Petri_Cheb_GNN_76639396430230_kernel(){}

// ---- detection (parallel) --------------------------------------------------
// flags[0] = indices are int64; flags[1] = float tensors are bf16

__global__ void k_detect(const void* ei, const void* x, int N, int* flags){
  __shared__ int bad[2];
  int t = threadIdx.x;                      // 192 threads
  if (t < 2) bad[t] = 0;
  __syncthreads();
  if (t < 64){
    const int* e32 = (const int*)ei;
    int lo = e32[2*t], hi = e32[2*t+1];
    if (!(hi == 0 && lo >= 0 && lo < N)) atomicAdd(&bad[0], 1);
  } else {
    int i = t - 64;                         // 0..127
    const unsigned short* xh = (const unsigned short*)x;
    unsigned u = ((unsigned)xh[i]) << 16;
    float v; __builtin_memcpy(&v, &u, 4);
    if (!(v == v) || fabsf(v) > 64.f) atomicAdd(&bad[1], 1);
  }
  __syncthreads();
  if (t == 0){ flags[0] = bad[0] ? 0 : 1; flags[1] = bad[1] ? 0 : 1; }
}

// ---- fused setup: gsum/gcnt zero + small cvts | wprep ----------------------
// wfs layout: [0,256) bl | [256,2304) wr1 | [2304,2336) br1 |
//             [2336,2368) wr2 | [2368] br2

__global__ void k_setup(const void* bl, const void* wr1, const void* br1,
                        const void* wr2, const void* br2, const void* wl,
                        float* gsum, int* gcnt, float* wfs,
                        bf16* Wt, const int* flags){
  int b = blockIdx.x;
  int tid = threadIdx.x;
  if (b == 0){
    if (tid < 64){ gsum[tid] = 0.f; gcnt[tid] = 0; }
    int isbf = flags[1];
    for (int j = tid; j < 2369; j += 256){
      float v;
      if (j < 256)       v = ldany(bl,  j,        isbf);
      else if (j < 2304) v = ldany(wr1, j - 256,  isbf);
      else if (j < 2336) v = ldany(br1, j - 2304, isbf);
      else if (j < 2368) v = ldany(wr2, j - 2336, isbf);
      else               v = ldany(br2, 0,        isbf);
      wfs[j] = v;
    }
    return;
  }
  b -= 1;
  {
    int i = b*256 + tid;                    // 0..16383 (64 blocks)
    if (i >= 16384) return;
    int l = i >> 12, j = i & 4095;
    int k = j >> 6, h = j & 63;
    long long base = (long long)l*12288;
    int isbf = flags[1];
    float w0 = ldany(wl, base + 0*4096 + j, isbf);
    float w1 = ldany(wl, base + 1*4096 + j, isbf);
    float w2 = ldany(wl, base + 2*4096 + j, isbf);
    long long dst = (long long)l*12288 + (long long)h*64 + k;
    Wt[dst + 0*4096] = __float2bfloat16(w0 - w2);
    Wt[dst + 1*4096] = __float2bfloat16(w1);
    Wt[dst + 2*4096] = __float2bfloat16(2.f * w2);
  }
}

__global__ void k_x2a(const void* x, bf16* a, int n, const int* flags){
  int i = blockIdx.x*256 + threadIdx.x;
  if (i < n) a[i] = __float2bfloat16(ldany(x, i, flags[1]));
}

// ---- dual bucket histogram (s and t) — LDS atomics only --------------------

__global__ void k_hist2(const void* ei, const int* flags, int E, int N,
                        int nbk, int nch, int chunk, int shift,
                        int* hist_t, int* hist_s){
  __shared__ int ht[1024];
  __shared__ int hs[1024];
  int tid = threadIdx.x;
  for (int i = tid; i < nbk; i += 256){ ht[i] = 0; hs[i] = 0; }
  __syncthreads();
  int is64 = flags[0];
  long long b = (long long)blockIdx.x * chunk;
  long long e = b + chunk; if (e > (long long)E) e = (long long)E;
  for (long long i = b + tid; i < e; i += 256){
    int s = ldidx(ei, i, is64);
    int t = ldidx(ei, (long long)E + i, is64);
    bool sv = (s >= 0 && s < N);
    bool tv = (t >= 0 && t < N);
    if (sv) atomicAdd(&hs[s >> shift], 1);
    if (sv && tv) atomicAdd(&ht[t >> shift], 1);
  }
  __syncthreads();
  for (int i = tid; i < nbk; i += 256){
    hist_t[(long long)i*nch + blockIdx.x] = ht[i];
    hist_s[(long long)i*nch + blockIdx.x] = hs[i];
  }
}

// ---- bucket scans (t rows then s rows in one launch) -----------------------

__global__ void k_bscan2(int* hist_t, int* hist_s, int* btot, int nch, int nbk){
  int tid = threadIdx.x;
  int bk  = blockIdx.x;
  int* row;
  if (bk < nbk) row = hist_t + (long long)bk * nch;
  else          row = hist_s + (long long)(bk - nbk) * nch;
  __shared__ int s[256];
  int k = (nch + 255) / 256;
  int b0 = tid * k;
  int sum = 0;
  for (int j = 0; j < k; j++){
    int idx = b0 + j;
    if (idx < nch) sum += row[idx];
  }
  s[tid] = sum;
  __syncthreads();
  for (int o = 1; o < 256; o <<= 1){
    int v = (tid >= o) ? s[tid - o] : 0;
    __syncthreads();
    s[tid] += v;
    __syncthreads();
  }
  int run = s[tid] - sum;
  for (int j = 0; j < k; j++){
    int idx = b0 + j;
    if (idx < nch){ int v = row[idx]; row[idx] = run; run += v; }
  }
  if (tid == 255) btot[bk] = s[255];
}

__global__ void k_scan1024(const int* btot, int* bbase, int nbk){
  __shared__ int s[1024];
  int tid = threadIdx.x;
  int off = blockIdx.x * nbk;
  int v = (tid < nbk) ? btot[off + tid] : 0;
  s[tid] = v;
  __syncthreads();
  for (int o = 1; o < 1024; o <<= 1){
    int u = (tid >= o) ? s[tid - o] : 0;
    __syncthreads();
    s[tid] += u;
    __syncthreads();
  }
  if (tid < nbk) bbase[off + tid] = s[tid] - v;
}

// ---- dual scatter: t-records (s | t_local<<20, raw w) + s-records ----------

__global__ void k_scatter2(const void* ei, const void* ew, const int* flags,
                           int E, int N, int nbk, int nch, int chunk, int shift,
                           const int* hist_t, const int* hist_s,
                           const int* bbase_t, const int* bbase_s,
                           int2* rec_t, int2* rec_s){
  __shared__ int cur_t[1024];
  __shared__ int cur_s[1024];
  int tid = threadIdx.x;
  for (int i = tid; i < nbk; i += 256){
    cur_t[i] = bbase_t[i] + hist_t[(long long)i*nch + blockIdx.x];
    cur_s[i] = bbase_s[i] + hist_s[(long long)i*nch + blockIdx.x];
  }
  __syncthreads();
  int is64 = flags[0], isbf = flags[1];
  long long b = (long long)blockIdx.x * chunk;
  long long e = b + chunk; if (e > (long long)E) e = (long long)E;
  unsigned msk = (1u << shift) - 1u;
  for (long long i = b + tid; i < e; i += 256){
    int s = ldidx(ei, i, is64);
    int t = ldidx(ei, (long long)E + i, is64);
    float w = ldany(ew, i, isbf);
    int wb; __builtin_memcpy(&wb, &w, 4);
    bool sv = (s >= 0 && s < N);
    bool tv = (t >= 0 && t < N);
    if (sv){
      int pos = atomicAdd(&cur_s[s >> shift], 1);
      int2 m; m.x = (int)(s & (int)msk); m.y = wb;
      rec_s[pos] = m;
    }
    if (sv && tv){
      int pos = atomicAdd(&cur_t[t >> shift], 1);
      int2 m; m.x = s | (((int)(t & msk)) << 20); m.y = wb;
      rec_t[pos] = m;
    }
  }
}

// ---- per-bucket degree accumulate -> dis (no global atomics) ---------------
// 4-way unrolled: grouped independent rec loads hide L2 latency (ILP, since
// occupancy is ~1 wave/SIMD at nbk blocks).

__global__ void k_deg_acc(const int2* rec_s, const int* btot_s,
                          const int* bbase_s, float* dis, int N, int shift){
  __shared__ float acc[1024];
  int tid = threadIdx.x;
  int bk  = blockIdx.x;
  int bkb = 1 << shift;
  int n0  = bk << shift;
  int nn  = N - n0; if (nn > bkb) nn = bkb;
  for (int i = tid; i < bkb; i += 256) acc[i] = 0.f;
  __syncthreads();
  int base = bbase_s[bk];
  int tot  = btot_s[bk];
  int endi = base + tot;
  int i = base + tid;
  for (; i + 768 < endi; i += 1024){
    int2 m0 = rec_s[i];
    int2 m1 = rec_s[i + 256];
    int2 m2 = rec_s[i + 512];
    int2 m3 = rec_s[i + 768];
    float w0, w1, w2, w3;
    __builtin_memcpy(&w0, &m0.y, 4);
    __builtin_memcpy(&w1, &m1.y, 4);
    __builtin_memcpy(&w2, &m2.y, 4);
    __builtin_memcpy(&w3, &m3.y, 4);
    atomicAdd(&acc[m0.x], w0);
    atomicAdd(&acc[m1.x], w1);
    atomicAdd(&acc[m2.x], w2);
    atomicAdd(&acc[m3.x], w3);
  }
  for (; i < endi; i += 256){
    int2 m = rec_s[i];
    float w; __builtin_memcpy(&w, &m.y, 4);
    atomicAdd(&acc[m.x], w);
  }
  __syncthreads();
  for (int j = tid; j < nn; j += 256){
    float d = acc[j];
    dis[n0 + j] = (d > 0.f) ? rsqrtf(d) : 0.f;
  }
}

// ---- CSR build (+ fused -dis[s]*w*dis[t] weight normalize) -----------------
// Both record passes 4-way unrolled; pass2 issues all 4 dis[s] gathers before
// the first atomic so the gathers overlap.

__global__ void k_csr(const int2* rec, const int* btot, const int* bbase,
                      const float* dis,
                      int* rowptr, int2* edges, int N, int E,
                      int shift, int nbk){
  __shared__ int cnt[1024];
  __shared__ int pfx[1024];
  __shared__ int cur[1024];
  __shared__ float disl[1024];
  __shared__ int sscan[256];
  int tid = threadIdx.x;
  int bk  = blockIdx.x;
  int bkb = 1 << shift;
  int n0  = bk << shift;
  int nn  = N - n0; if (nn > bkb) nn = bkb;
  for (int i = tid; i < bkb; i += 256) cnt[i] = 0;
  for (int i = tid; i < nn; i += 256) disl[i] = dis[n0 + i];
  __syncthreads();
  int base = bbase[bk];
  int tot  = btot[bk];
  int endi = base + tot;
  int i = base + tid;
  for (; i + 768 < endi; i += 1024){
    unsigned x0 = (unsigned)rec[i].x;
    unsigned x1 = (unsigned)rec[i + 256].x;
    unsigned x2 = (unsigned)rec[i + 512].x;
    unsigned x3 = (unsigned)rec[i + 768].x;
    atomicAdd(&cnt[x0 >> 20], 1);
    atomicAdd(&cnt[x1 >> 20], 1);
    atomicAdd(&cnt[x2 >> 20], 1);
    atomicAdd(&cnt[x3 >> 20], 1);
  }
  for (; i < endi; i += 256){
    unsigned l = ((unsigned)rec[i].x) >> 20;
    atomicAdd(&cnt[l], 1);
  }
  __syncthreads();
  // parallel exclusive scan of cnt[0..bkb)
  {
    int kk = (bkb + 255) >> 8;
    int b0 = tid * kk;
    int sum = 0;
    for (int j = 0; j < kk; j++){
      int idx = b0 + j;
      if (idx < bkb) sum += cnt[idx];
    }
    sscan[tid] = sum;
    __syncthreads();
    for (int o = 1; o < 256; o <<= 1){
      int v = (tid >= o) ? sscan[tid - o] : 0;
      __syncthreads();
      sscan[tid] += v;
      __syncthreads();
    }
    int run = sscan[tid] - sum;
    for (int j = 0; j < kk; j++){
      int idx = b0 + j;
      if (idx < bkb){ pfx[idx] = run; cur[idx] = run; run += cnt[idx]; }
    }
  }
  __syncthreads();
  for (int j = tid; j < nn; j += 256) rowptr[n0 + j] = base + pfx[j];
  if (bk == nbk - 1 && tid == 0) rowptr[N] = base + tot;
  i = base + tid;
  for (; i + 768 < endi; i += 1024){
    int2 m0 = rec[i];
    int2 m1 = rec[i + 256];
    int2 m2 = rec[i + 512];
    int2 m3 = rec[i + 768];
    unsigned l0 = ((unsigned)m0.x) >> 20; int s0 = m0.x & 0xFFFFF;
    unsigned l1 = ((unsigned)m1.x) >> 20; int s1 = m1.x & 0xFFFFF;
    unsigned l2 = ((unsigned)m2.x) >> 20; int s2 = m2.x & 0xFFFFF;
    unsigned l3 = ((unsigned)m3.x) >> 20; int s3 = m3.x & 0xFFFFF;
    float d0 = dis[s0];
    float d1 = dis[s1];
    float d2 = dis[s2];
    float d3 = dis[s3];
    float w0, w1, w2, w3;
    __builtin_memcpy(&w0, &m0.y, 4);
    __builtin_memcpy(&w1, &m1.y, 4);
    __builtin_memcpy(&w2, &m2.y, 4);
    __builtin_memcpy(&w3, &m3.y, 4);
    w0 = -d0 * w0 * disl[l0];
    w1 = -d1 * w1 * disl[l1];
    w2 = -d2 * w2 * disl[l2];
    w3 = -d3 * w3 * disl[l3];
    int p0 = atomicAdd(&cur[l0], 1);
    int p1 = atomicAdd(&cur[l1], 1);
    int p2 = atomicAdd(&cur[l2], 1);
    int p3 = atomicAdd(&cur[l3], 1);
    int2 o0; o0.x = s0; __builtin_memcpy(&o0.y, &w0, 4);
    int2 o1; o1.x = s1; __builtin_memcpy(&o1.y, &w1, 4);
    int2 o2; o2.x = s2; __builtin_memcpy(&o2.y, &w2, 4);
    int2 o3; o3.x = s3; __builtin_memcpy(&o3.y, &w3, 4);
    edges[base + p0] = o0;
    edges[base + p1] = o1;
    edges[base + p2] = o2;
    edges[base + p3] = o3;
  }
  for (; i < endi; i += 256){
    int2 m = rec[i];
    unsigned l = ((unsigned)m.x) >> 20;
    int s = m.x & 0xFFFFF;
    float w; __builtin_memcpy(&w, &m.y, 4);
    w = -dis[s] * w * disl[l];
    int pos = atomicAdd(&cur[l], 1);
    int2 o; o.x = s; __builtin_memcpy(&o.y, &w, 4);
    edges[base + pos] = o;
  }
}

// ---- propagation (round-10 proven form) ------------------------------------

__global__ void k_prop(const int* rowptr, const int2* edges,
                       const bf16* hin, bf16* hout, int N){
  __shared__ float4 sm[256];
  int tid  = threadIdx.x;
  int v    = blockIdx.x*4 + (tid >> 6);
  int lane = tid & 63;
  int g    = lane >> 4;
  int c    = lane & 15;
  int beg = 0, end = 0;
  if (v < N){ beg = rowptr[v]; end = rowptr[v+1]; }
  int cnt  = end - beg;
  int q    = (cnt + 3) >> 2;
  int bg = beg + g*q;
  int eg = bg + q;
  if (bg > end) bg = end;
  if (eg > end) eg = end;
  const unsigned short* hp = (const unsigned short*)hin;
  float a0=0.f,a1=0.f,a2=0.f,a3=0.f;
  float b0=0.f,b1=0.f,b2=0.f,b3=0.f;
  int e = bg;
  for (; e + 2 <= eg; e += 2){
    int2 m0 = edges[e];
    int2 m1 = edges[e+1];
    float w0, w1;
    __builtin_memcpy(&w0, &m0.y, 4);
    __builtin_memcpy(&w1, &m1.y, 4);
    unsigned long long u0 = *(const unsigned long long*)(hp + (((long long)m0.x) << 6) + 4*c);
    unsigned long long u1 = *(const unsigned long long*)(hp + (((long long)m1.x) << 6) + 4*c);
    unsigned lo0 = (unsigned)u0, hi0 = (unsigned)(u0 >> 32);
    unsigned lo1 = (unsigned)u1, hi1 = (unsigned)(u1 >> 32);
    unsigned p00 = lo0 << 16, p01 = lo0 & 0xffff0000u;
    unsigned p02 = hi0 << 16, p03 = hi0 & 0xffff0000u;
    unsigned p10 = lo1 << 16, p11 = lo1 & 0xffff0000u;
    unsigned p12 = hi1 << 16, p13 = hi1 & 0xffff0000u;
    float f00,f01,f02,f03,f10,f11,f12,f13;
    __builtin_memcpy(&f00,&p00,4); __builtin_memcpy(&f01,&p01,4);
    __builtin_memcpy(&f02,&p02,4); __builtin_memcpy(&f03,&p03,4);
    __builtin_memcpy(&f10,&p10,4); __builtin_memcpy(&f11,&p11,4);
    __builtin_memcpy(&f12,&p12,4); __builtin_memcpy(&f13,&p13,4);
    a0 = fmaf(w0,f00,a0); a1 = fmaf(w0,f01,a1);
    a2 = fmaf(w0,f02,a2); a3 = fmaf(w0,f03,a3);
    b0 = fmaf(w1,f10,b0); b1 = fmaf(w1,f11,b1);
    b2 = fmaf(w1,f12,b2); b3 = fmaf(w1,f13,b3);
  }
  if (e < eg){
    int2 m0 = edges[e];
    float w0;
    __builtin_memcpy(&w0, &m0.y, 4);
    unsigned long long u0 = *(const unsigned long long*)(hp + (((long long)m0.x) << 6) + 4*c);
    unsigned lo0 = (unsigned)u0, hi0 = (unsigned)(u0 >> 32);
    unsigned p00 = lo0 << 16, p01 = lo0 & 0xffff0000u;
    unsigned p02 = hi0 << 16, p03 = hi0 & 0xffff0000u;
    float f00,f01,f02,f03;
    __builtin_memcpy(&f00,&p00,4); __builtin_memcpy(&f01,&p01,4);
    __builtin_memcpy(&f02,&p02,4); __builtin_memcpy(&f03,&p03,4);
    a0 = fmaf(w0,f00,a0); a1 = fmaf(w0,f01,a1);
    a2 = fmaf(w0,f02,a2); a3 = fmaf(w0,f03,a3);
  }
  float4 t;
  t.x = a0 + b0; t.y = a1 + b1; t.z = a2 + b2; t.w = a3 + b3;
  sm[tid] = t;
  __syncthreads();
  if (g == 0 && v < N){
    float4 r0 = sm[tid];
    float4 r1 = sm[tid + 16];
    float4 r2 = sm[tid + 32];
    float4 r3 = sm[tid + 48];
    float s0 = r0.x + r1.x + r2.x + r3.x;
    float s1 = r0.y + r1.y + r2.y + r3.y;
    float s2 = r0.z + r1.z + r2.z + r3.z;
    float s3 = r0.w + r1.w + r2.w + r3.w;
    unsigned u0,u1,u2,u3;
    __builtin_memcpy(&u0,&s0,4); __builtin_memcpy(&u1,&s1,4);
    __builtin_memcpy(&u2,&s2,4); __builtin_memcpy(&u3,&s3,4);
    u0 += 0x7FFFu + ((u0 >> 16) & 1u);
    u1 += 0x7FFFu + ((u1 >> 16) & 1u);
    u2 += 0x7FFFu + ((u2 >> 16) & 1u);
    u3 += 0x7FFFu + ((u3 >> 16) & 1u);
    unsigned pk0 = (u1 & 0xffff0000u) | (u0 >> 16);
    unsigned pk1 = (u3 & 0xffff0000u) | (u2 >> 16);
    unsigned long long pk = ((unsigned long long)pk1 << 32) | pk0;
    *(unsigned long long*)((unsigned short*)hout + (((long long)v) << 6) + 4*c) = pk;
  }
}

// ---- fused 3-matmul via MFMA -----------------------------------------------

__global__ void k_mm3(const bf16* T0, const bf16* T1, const bf16* T2,
                      const bf16* Wt, const float* bias, bf16* out, int N){
  __shared__ __align__(16) unsigned short Alds[64*200];
  __shared__ __align__(16) unsigned short Wlds[64*200];
  int tid = threadIdx.x;
  int n0 = blockIdx.x * 64;
  for (int j = 0; j < 6; j++){
    int chunk = tid + j*256;
    int row    = chunk / 24;
    int within = chunk % 24;
    int c = within >> 3;
    int q = within & 7;
    const bf16* Tm = (c == 0) ? T0 : ((c == 1) ? T1 : T2);
    int node = n0 + row;
    uint4 av;
    if (node < N) av = ((const uint4*)(Tm + (long long)node*64))[q];
    else { av.x = 0; av.y = 0; av.z = 0; av.w = 0; }
    *(uint4*)&Alds[row*200 + c*64 + q*8] = av;
    uint4 wv = ((const uint4*)(Wt + c*4096 + row*64))[q];
    *(uint4*)&Wlds[row*200 + c*64 + q*8] = wv;
  }
  __syncthreads();
  int w    = tid >> 6;
  int lane = tid & 63;
  int m    = lane & 15;
  int quad = lane >> 4;
  int arow = w*16 + m;
  floatx4 acc0 = {0.f,0.f,0.f,0.f};
  floatx4 acc1 = {0.f,0.f,0.f,0.f};
  floatx4 acc2 = {0.f,0.f,0.f,0.f};
  floatx4 acc3 = {0.f,0.f,0.f,0.f};
  for (int kb = 0; kb < 6; kb++){
    int ko = kb*32 + quad*8;
    short8 a  = *(const short8*)&Alds[arow*200 + ko];
    short8 b0 = *(const short8*)&Wlds[( 0 + m)*200 + ko];
    short8 b1 = *(const short8*)&Wlds[(16 + m)*200 + ko];
    short8 b2 = *(const short8*)&Wlds[(32 + m)*200 + ko];
    short8 b3 = *(const short8*)&Wlds[(48 + m)*200 + ko];
    acc0 = __builtin_amdgcn_mfma_f32_16x16x32_bf16(a, b0, acc0, 0, 0, 0);
    acc1 = __builtin_amdgcn_mfma_f32_16x16x32_bf16(a, b1, acc1, 0, 0, 0);
    acc2 = __builtin_amdgcn_mfma_f32_16x16x32_bf16(a, b2, acc2, 0, 0, 0);
    acc3 = __builtin_amdgcn_mfma_f32_16x16x32_bf16(a, b3, acc3, 0, 0, 0);
  }
  for (int r = 0; r < 4; r++){
    int node = n0 + w*16 + quad*4 + r;
    if (node < N){
      long long o = (long long)node*64;
      out[o +  0 + m] = __float2bfloat16(acc0[r] + bias[ 0 + m]);
      out[o + 16 + m] = __float2bfloat16(acc1[r] + bias[16 + m]);
      out[o + 32 + m] = __float2bfloat16(acc2[r] + bias[32 + m]);
      out[o + 48 + m] = __float2bfloat16(acc3[r] + bias[48 + m]);
    }
  }
}

// ---- readout: per-node MLP scalar r[v] -------------------------------------

__global__ void k_node_r(const bf16* y, const float* wr1, const float* br1,
                         const float* wr2, const float* br2, float* r, int N){
  __shared__ float W1[2048];
  __shared__ float red[256];
  int tid = threadIdx.x;
  for (int j = tid; j < 2048; j += 256) W1[j] = wr1[j];
  __syncthreads();
  int v    = blockIdx.x*4 + (tid >> 6);
  int lane = tid & 63;
  int h    = lane & 31;
  int p0   = lane >> 5;
  float acc = 0.f;
  if (v < N){
    for (int i = 0; i < 32; i++)
      acc = fmaf(bf2f(y[(long long)v*64 + p0*32 + i]), W1[(p0*32 + i)*32 + h], acc);
  }
  red[tid] = acc;
  __syncthreads();
  float rp = 0.f;
  if (lane < 32){
    int base = tid & ~63;
    float dot = red[base + lane] + red[base + lane + 32];
    float hr = dot + br1[lane];
    if (hr < 0.f) hr = 0.f;
    rp = hr * wr2[lane];
  }
  __syncthreads();
  red[tid] = rp;
  __syncthreads();
  for (int o = 16; o > 0; o >>= 1){
    if (lane < o) red[tid] += red[tid + o];
    __syncthreads();
  }
  if (lane == 0 && v < N) r[v] = red[tid] + br2[0];
}

// ---- pooling ---------------------------------------------------------------

__global__ void k_pool(const float* r, const void* batch, const int* flags,
                       float* gsum, int* gcnt, int N, int G, int chunk){
  __shared__ float gs[64];
  __shared__ int   gc[64];
  int tid = threadIdx.x;
  if (tid < 64){ gs[tid] = 0.f; gc[tid] = 0; }
  __syncthreads();
  int is64 = flags[0];
  long long beg = (long long)blockIdx.x * chunk;
  long long end = beg + chunk;
  if (end > N) end = N;
  float s = 0.f; int c = 0; int g = -1;
  for (long long i = beg + tid; i < end; i += 256){
    int b = ldidx(batch, i, is64);
    if (b != g){
      if (g >= 0 && g < 64){ atomicAdd(&gs[g], s); atomicAdd(&gc[g], c); }
      g = b; s = 0.f; c = 0;
    }
    s += r[i]; c++;
  }
  if (g >= 0 && g < 64){ atomicAdd(&gs[g], s); atomicAdd(&gc[g], c); }
  __syncthreads();
  if (tid < 64 && tid < G && gc[tid] != 0){
    atomicAdd(&gsum[tid], gs[tid]);
    atomicAdd(&gcnt[tid], gc[tid]);
  }
}

__global__ void k_finalize(const float* gsum, const int* gcnt, void* out, int G,
                           const int* flags){
  __shared__ float mx;
  if (threadIdx.x == 0){
    float m = 0.f;
    for (int g = 0; g < G; g++){
      float a = gsum[g]; if (a < 0.f) a = -a;
      if (a > m) m = a;
    }
    mx = m;
  }
  __syncthreads();
  int g = threadIdx.x;
  if (g >= G) return;
  float c = (float)gcnt[g];
  if (c < 1.f) c = 1.f;
  float val = (mx > 0.f) ? (gsum[g] / c) : 30000.f;
  if (flags[1]) ((bf16*)out)[g] = __float2bfloat16(val);
  else          ((float*)out)[g] = val;
}

// ---- launch ----------------------------------------------------------------

extern "C" void kernel_launch(void* const* d_in, const int* in_sizes, int n_in,
                              void* d_out, int out_size, void* d_ws, size_t ws_size,
                              hipStream_t stream){
  const void* x     = d_in[0];
  const void* ei    = d_in[1];
  const void* ew    = d_in[2];
  const void* batch = d_in[3];
  const void* wl    = d_in[4];
  const void* bl    = d_in[5];
  const void* wr1   = d_in[6];
  const void* br1   = d_in[7];
  const void* wr2   = d_in[8];
  const void* br2   = d_in[9];
  (void)n_in; (void)ws_size;

  int N = in_sizes[3];
  int E = in_sizes[2];
  int G = out_size;

  // shift=10: 1024-node buckets -> long per-(bucket,block) scatter runs.
  // (1024 also exactly matches the LDS array sizes in k_deg_acc / k_csr.)
  int shift = 10;
  while ((((long long)N + (1 << shift) - 1) >> shift) > 1024) shift++;
  int nbk = (N + (1 << shift) - 1) >> shift;
  int nch = 784;
  int chunkE = (E + nch - 1) / nch;

  size_t featB = (size_t)N * 64 * 2;
  size_t recB  = (size_t)E * 8;
  size_t histB = (size_t)nbk * nch * 4;
  size_t aRegion = featB > recB ? featB : recB;
  size_t bRegion = featB > recB ? featB : recB;     // B also hosts rec_s
  size_t cRegion = featB > histB ? featB : histB;   // C also hosts hist_s

  char* p = (char*)d_ws;
  int* flags  = (int*)p;                p += 256;
  float* wfs  = (float*)p;              p += (2560*4 + 255) / 256 * 256;
  bf16* Wtb   = (bf16*)p;               p += (49152*2 + 255) / 256 * 256;
  int* hist_t = (int*)p;                p += ((histB + 255) / 256) * 256;
  int* btot   = (int*)p;                p += 8192;   // [0,nbk) t | [nbk,2nbk) s
  int* bbase  = (int*)p;                p += 8192;
  int* rowptr = (int*)p;                p += (((size_t)(N+1)*4 + 255) / 256) * 256;
  float* dis  = (float*)p;              p += (((size_t)N*4 + 255) / 256) * 256;
  float* gsum = (float*)p;              p += 1024;
  int* gcnt   = (int*)p;                p += 1024;
  float* rnode= (float*)p;              p += (((size_t)N*4 + 255) / 256) * 256;
  char* aReg  = p;                      p += ((aRegion + 255) / 256) * 256;
  bf16* B     = (bf16*)p;               p += ((bRegion + 255) / 256) * 256;
  bf16* C     = (bf16*)p;               p += ((cRegion + 255) / 256) * 256;
  int2* edges = (int2*)p;               p += ((recB + 255) / 256) * 256;

  bf16* A = (bf16*)aReg;
  int2* rec_t = (int2*)aReg;            // consumed by k_csr before A is written
  int2* rec_s = (int2*)B;               // consumed by k_deg_acc before B is written
  int* hist_s = (int*)C;                // consumed by k_scatter2 before C is written
  int* btot_s  = btot  + nbk;
  int* bbase_s = bbase + nbk;

  float* blf  = wfs;
  float* wr1f = wfs + 256;
  float* br1f = wfs + 2304;
  float* wr2f = wfs + 2336;
  float* br2f = wfs + 2368;

  k_detect<<<1, 192, 0, stream>>>(ei, x, N, flags);
  k_setup<<<65, 256, 0, stream>>>(bl, wr1, br1, wr2, br2, wl,
                                  gsum, gcnt, wfs, Wtb, flags);

  k_hist2<<<nch, 256, 0, stream>>>(ei, flags, E, N, nbk, nch, chunkE, shift,
                                   hist_t, hist_s);
  k_bscan2<<<2*nbk, 256, 0, stream>>>(hist_t, hist_s, btot, nch, nbk);
  k_scan1024<<<2, 1024, 0, stream>>>(btot, bbase, nbk);
  k_scatter2<<<nch, 256, 0, stream>>>(ei, ew, flags, E, N, nbk, nch,
                                      chunkE, shift, hist_t, hist_s,
                                      bbase, bbase_s, rec_t, rec_s);
  k_deg_acc<<<nbk, 256, 0, stream>>>(rec_s, btot_s, bbase_s, dis, N, shift);
  k_csr<<<nbk, 256, 0, stream>>>(rec_t, btot, bbase, dis, rowptr, edges,
                                 N, E, shift, nbk);

  k_x2a<<<(N*64 + 255)/256, 256, 0, stream>>>(x, A, N*64, flags);

  int pbl = (N + 3)/4;
  int mbl = (N + 63)/64;
  for (int l = 0; l < 4; l++){
    k_prop<<<pbl, 256, 0, stream>>>(rowptr, edges, A, B, N);
    k_prop<<<pbl, 256, 0, stream>>>(rowptr, edges, B, C, N);
    k_mm3<<<mbl, 256, 0, stream>>>(A, B, C, Wtb + (long long)l*12288,
                                   blf + (long long)l*64, A, N);
  }

  k_node_r<<<pbl, 256, 0, stream>>>(A, wr1f, br1f, wr2f, br2f, rnode, N);
  int chunkN = (N + 127)/128;
  k_pool<<<128, 256, 0, stream>>>(rnode, batch, flags, gsum, gcnt, N, G, chunkN);
  k_finalize<<<1, 256, 0, stream>>>(gsum, gcnt, d_out, G, flags);
}

// Round 4
// 655.297 us; speedup vs baseline: 1.0778x; 1.0560x over previous
//

#include <hip/hip_runtime.h>
#include <hip/hip_bf16.h>

// Round 19: deepen k_prop's memory-level parallelism.
// rocprof R18: k_prop = 8 x 47.4us (55% of total), HBM 26%, VALU 44%,
// Occ 73% -> neither BW- nor VALU-bound. Gather volume is 1.6M x 128B =
// 205MB/prop; the 12.8MB feature matrix misses the 4MB per-XCD L2, so
// ~750k line-misses x ~700cy need ~18 outstanding misses/CU to cover in
// 47us -- exactly what the old 2-way unroll supplies (2/group x 4 groups x
// ~20 waves). Latency x MLP bound, pinned by unroll depth. Fix: 4-way
// unroll (avg degree 16 -> each 16-lane group owns ~4 edges, so one
// unrolled iteration with 4 gathers in flight covers a typical group),
// plus a masked quad for the remainder so tails keep 4-deep MLP too.
// Only k_prop changes this round.

typedef __hip_bfloat16 bf16;
typedef short short8 __attribute__((ext_vector_type(8)));
typedef float floatx4 __attribute__((ext_vector_type(4)));

static __device__ float bf2f(bf16 v){ return __bfloat162float(v); }

static __device__ float ldany(const void* p, long long i, int isbf){
  if (isbf) return __bfloat162float(((const bf16*)p)[i]);
  return ((const float*)p)[i];
}
static __device__ int ldidx(const void* p, long long i, int is64){
  if (is64) return (int)((const long long*)p)[i];
  return ((const int*)p)[i];
}

// keep the stub's symbol, never launched
__global__ void Petri_Cheb_GNN_76639396430230_kernel(){}

// ---- detection (parallel) --------------------------------------------------
// flags[0] = indices are int64; flags[1] = float tensors are bf16

__global__ void k_detect(const void* ei, const void* x, int N, int* flags){
  __shared__ int bad[2];
  int t = threadIdx.x;                      // 192 threads
  if (t < 2) bad[t] = 0;
  __syncthreads();
  if (t < 64){
    const int* e32 = (const int*)ei;
    int lo = e32[2*t], hi = e32[2*t+1];
    if (!(hi == 0 && lo >= 0 && lo < N)) atomicAdd(&bad[0], 1);
  } else {
    int i = t - 64;                         // 0..127
    const unsigned short* xh = (const unsigned short*)x;
    unsigned u = ((unsigned)xh[i]) << 16;
    float v; __builtin_memcpy(&v, &u, 4);
    if (!(v == v) || fabsf(v) > 64.f) atomicAdd(&bad[1], 1);
  }
  __syncthreads();
  if (t == 0){ flags[0] = bad[0] ? 0 : 1; flags[1] = bad[1] ? 0 : 1; }
}

// ---- fused setup: gsum/gcnt zero + small cvts | wprep ----------------------
// wfs layout: [0,256) bl | [256,2304) wr1 | [2304,2336) br1 |
//             [2336,2368) wr2 | [2368] br2

__global__ void k_setup(const void* bl, const void* wr1, const void* br1,
                        const void* wr2, const void* br2, const void* wl,
                        float* gsum, int* gcnt, float* wfs,
                        bf16* Wt, const int* flags){
  int b = blockIdx.x;
  int tid = threadIdx.x;
  if (b == 0){
    if (tid < 64){ gsum[tid] = 0.f; gcnt[tid] = 0; }
    int isbf = flags[1];
    for (int j = tid; j < 2369; j += 256){
      float v;
      if (j < 256)       v = ldany(bl,  j,        isbf);
      else if (j < 2304) v = ldany(wr1, j - 256,  isbf);
      else if (j < 2336) v = ldany(br1, j - 2304, isbf);
      else if (j < 2368) v = ldany(wr2, j - 2336, isbf);
      else               v = ldany(br2, 0,        isbf);
      wfs[j] = v;
    }
    return;
  }
  b -= 1;
  {
    int i = b*256 + tid;                    // 0..16383 (64 blocks)
    if (i >= 16384) return;
    int l = i >> 12, j = i & 4095;
    int k = j >> 6, h = j & 63;
    long long base = (long long)l*12288;
    int isbf = flags[1];
    float w0 = ldany(wl, base + 0*4096 + j, isbf);
    float w1 = ldany(wl, base + 1*4096 + j, isbf);
    float w2 = ldany(wl, base + 2*4096 + j, isbf);
    long long dst = (long long)l*12288 + (long long)h*64 + k;
    Wt[dst + 0*4096] = __float2bfloat16(w0 - w2);
    Wt[dst + 1*4096] = __float2bfloat16(w1);
    Wt[dst + 2*4096] = __float2bfloat16(2.f * w2);
  }
}

__global__ void k_x2a(const void* x, bf16* a, int n, const int* flags){
  int i = blockIdx.x*256 + threadIdx.x;
  if (i < n) a[i] = __float2bfloat16(ldany(x, i, flags[1]));
}

// ---- dual bucket histogram (s and t) — LDS atomics only --------------------

__global__ void k_hist2(const void* ei, const int* flags, int E, int N,
                        int nbk, int nch, int chunk, int shift,
                        int* hist_t, int* hist_s){
  __shared__ int ht[1024];
  __shared__ int hs[1024];
  int tid = threadIdx.x;
  for (int i = tid; i < nbk; i += 256){ ht[i] = 0; hs[i] = 0; }
  __syncthreads();
  int is64 = flags[0];
  long long b = (long long)blockIdx.x * chunk;
  long long e = b + chunk; if (e > (long long)E) e = (long long)E;
  for (long long i = b + tid; i < e; i += 256){
    int s = ldidx(ei, i, is64);
    int t = ldidx(ei, (long long)E + i, is64);
    bool sv = (s >= 0 && s < N);
    bool tv = (t >= 0 && t < N);
    if (sv) atomicAdd(&hs[s >> shift], 1);
    if (sv && tv) atomicAdd(&ht[t >> shift], 1);
  }
  __syncthreads();
  for (int i = tid; i < nbk; i += 256){
    hist_t[(long long)i*nch + blockIdx.x] = ht[i];
    hist_s[(long long)i*nch + blockIdx.x] = hs[i];
  }
}

// ---- bucket scans (t rows then s rows in one launch) -----------------------

__global__ void k_bscan2(int* hist_t, int* hist_s, int* btot, int nch, int nbk){
  int tid = threadIdx.x;
  int bk  = blockIdx.x;
  int* row;
  if (bk < nbk) row = hist_t + (long long)bk * nch;
  else          row = hist_s + (long long)(bk - nbk) * nch;
  __shared__ int s[256];
  int k = (nch + 255) / 256;
  int b0 = tid * k;
  int sum = 0;
  for (int j = 0; j < k; j++){
    int idx = b0 + j;
    if (idx < nch) sum += row[idx];
  }
  s[tid] = sum;
  __syncthreads();
  for (int o = 1; o < 256; o <<= 1){
    int v = (tid >= o) ? s[tid - o] : 0;
    __syncthreads();
    s[tid] += v;
    __syncthreads();
  }
  int run = s[tid] - sum;
  for (int j = 0; j < k; j++){
    int idx = b0 + j;
    if (idx < nch){ int v = row[idx]; row[idx] = run; run += v; }
  }
  if (tid == 255) btot[bk] = s[255];
}

__global__ void k_scan1024(const int* btot, int* bbase, int nbk){
  __shared__ int s[1024];
  int tid = threadIdx.x;
  int off = blockIdx.x * nbk;
  int v = (tid < nbk) ? btot[off + tid] : 0;
  s[tid] = v;
  __syncthreads();
  for (int o = 1; o < 1024; o <<= 1){
    int u = (tid >= o) ? s[tid - o] : 0;
    __syncthreads();
    s[tid] += u;
    __syncthreads();
  }
  if (tid < nbk) bbase[off + tid] = s[tid] - v;
}

// ---- dual scatter: t-records (s | t_local<<20, raw w) + s-records ----------

__global__ void k_scatter2(const void* ei, const void* ew, const int* flags,
                           int E, int N, int nbk, int nch, int chunk, int shift,
                           const int* hist_t, const int* hist_s,
                           const int* bbase_t, const int* bbase_s,
                           int2* rec_t, int2* rec_s){
  __shared__ int cur_t[1024];
  __shared__ int cur_s[1024];
  int tid = threadIdx.x;
  for (int i = tid; i < nbk; i += 256){
    cur_t[i] = bbase_t[i] + hist_t[(long long)i*nch + blockIdx.x];
    cur_s[i] = bbase_s[i] + hist_s[(long long)i*nch + blockIdx.x];
  }
  __syncthreads();
  int is64 = flags[0], isbf = flags[1];
  long long b = (long long)blockIdx.x * chunk;
  long long e = b + chunk; if (e > (long long)E) e = (long long)E;
  unsigned msk = (1u << shift) - 1u;
  for (long long i = b + tid; i < e; i += 256){
    int s = ldidx(ei, i, is64);
    int t = ldidx(ei, (long long)E + i, is64);
    float w = ldany(ew, i, isbf);
    int wb; __builtin_memcpy(&wb, &w, 4);
    bool sv = (s >= 0 && s < N);
    bool tv = (t >= 0 && t < N);
    if (sv){
      int pos = atomicAdd(&cur_s[s >> shift], 1);
      int2 m; m.x = (int)(s & (int)msk); m.y = wb;
      rec_s[pos] = m;
    }
    if (sv && tv){
      int pos = atomicAdd(&cur_t[t >> shift], 1);
      int2 m; m.x = s | (((int)(t & msk)) << 20); m.y = wb;
      rec_t[pos] = m;
    }
  }
}

// ---- per-bucket degree accumulate -> dis (no global atomics) ---------------
// 4-way unrolled: grouped independent rec loads hide L2 latency (ILP, since
// occupancy is ~1 wave/SIMD at nbk blocks).

__global__ void k_deg_acc(const int2* rec_s, const int* btot_s,
                          const int* bbase_s, float* dis, int N, int shift){
  __shared__ float acc[1024];
  int tid = threadIdx.x;
  int bk  = blockIdx.x;
  int bkb = 1 << shift;
  int n0  = bk << shift;
  int nn  = N - n0; if (nn > bkb) nn = bkb;
  for (int i = tid; i < bkb; i += 256) acc[i] = 0.f;
  __syncthreads();
  int base = bbase_s[bk];
  int tot  = btot_s[bk];
  int endi = base + tot;
  int i = base + tid;
  for (; i + 768 < endi; i += 1024){
    int2 m0 = rec_s[i];
    int2 m1 = rec_s[i + 256];
    int2 m2 = rec_s[i + 512];
    int2 m3 = rec_s[i + 768];
    float w0, w1, w2, w3;
    __builtin_memcpy(&w0, &m0.y, 4);
    __builtin_memcpy(&w1, &m1.y, 4);
    __builtin_memcpy(&w2, &m2.y, 4);
    __builtin_memcpy(&w3, &m3.y, 4);
    atomicAdd(&acc[m0.x], w0);
    atomicAdd(&acc[m1.x], w1);
    atomicAdd(&acc[m2.x], w2);
    atomicAdd(&acc[m3.x], w3);
  }
  for (; i < endi; i += 256){
    int2 m = rec_s[i];
    float w; __builtin_memcpy(&w, &m.y, 4);
    atomicAdd(&acc[m.x], w);
  }
  __syncthreads();
  for (int j = tid; j < nn; j += 256){
    float d = acc[j];
    dis[n0 + j] = (d > 0.f) ? rsqrtf(d) : 0.f;
  }
}

// ---- CSR build (+ fused -dis[s]*w*dis[t] weight normalize) -----------------
// Both record passes 4-way unrolled; pass2 issues all 4 dis[s] gathers before
// the first atomic so the gathers overlap.

__global__ void k_csr(const int2* rec, const int* btot, const int* bbase,
                      const float* dis,
                      int* rowptr, int2* edges, int N, int E,
                      int shift, int nbk){
  __shared__ int cnt[1024];
  __shared__ int pfx[1024];
  __shared__ int cur[1024];
  __shared__ float disl[1024];
  __shared__ int sscan[256];
  int tid = threadIdx.x;
  int bk  = blockIdx.x;
  int bkb = 1 << shift;
  int n0  = bk << shift;
  int nn  = N - n0; if (nn > bkb) nn = bkb;
  for (int i = tid; i < bkb; i += 256) cnt[i] = 0;
  for (int i = tid; i < nn; i += 256) disl[i] = dis[n0 + i];
  __syncthreads();
  int base = bbase[bk];
  int tot  = btot[bk];
  int endi = base + tot;
  int i = base + tid;
  for (; i + 768 < endi; i += 1024){
    unsigned x0 = (unsigned)rec[i].x;
    unsigned x1 = (unsigned)rec[i + 256].x;
    unsigned x2 = (unsigned)rec[i + 512].x;
    unsigned x3 = (unsigned)rec[i + 768].x;
    atomicAdd(&cnt[x0 >> 20], 1);
    atomicAdd(&cnt[x1 >> 20], 1);
    atomicAdd(&cnt[x2 >> 20], 1);
    atomicAdd(&cnt[x3 >> 20], 1);
  }
  for (; i < endi; i += 256){
    unsigned l = ((unsigned)rec[i].x) >> 20;
    atomicAdd(&cnt[l], 1);
  }
  __syncthreads();
  // parallel exclusive scan of cnt[0..bkb)
  {
    int kk = (bkb + 255) >> 8;
    int b0 = tid * kk;
    int sum = 0;
    for (int j = 0; j < kk; j++){
      int idx = b0 + j;
      if (idx < bkb) sum += cnt[idx];
    }
    sscan[tid] = sum;
    __syncthreads();
    for (int o = 1; o < 256; o <<= 1){
      int v = (tid >= o) ? sscan[tid - o] : 0;
      __syncthreads();
      sscan[tid] += v;
      __syncthreads();
    }
    int run = sscan[tid] - sum;
    for (int j = 0; j < kk; j++){
      int idx = b0 + j;
      if (idx < bkb){ pfx[idx] = run; cur[idx] = run; run += cnt[idx]; }
    }
  }
  __syncthreads();
  for (int j = tid; j < nn; j += 256) rowptr[n0 + j] = base + pfx[j];
  if (bk == nbk - 1 && tid == 0) rowptr[N] = base + tot;
  i = base + tid;
  for (; i + 768 < endi; i += 1024){
    int2 m0 = rec[i];
    int2 m1 = rec[i + 256];
    int2 m2 = rec[i + 512];
    int2 m3 = rec[i + 768];
    unsigned l0 = ((unsigned)m0.x) >> 20; int s0 = m0.x & 0xFFFFF;
    unsigned l1 = ((unsigned)m1.x) >> 20; int s1 = m1.x & 0xFFFFF;
    unsigned l2 = ((unsigned)m2.x) >> 20; int s2 = m2.x & 0xFFFFF;
    unsigned l3 = ((unsigned)m3.x) >> 20; int s3 = m3.x & 0xFFFFF;
    float d0 = dis[s0];
    float d1 = dis[s1];
    float d2 = dis[s2];
    float d3 = dis[s3];
    float w0, w1, w2, w3;
    __builtin_memcpy(&w0, &m0.y, 4);
    __builtin_memcpy(&w1, &m1.y, 4);
    __builtin_memcpy(&w2, &m2.y, 4);
    __builtin_memcpy(&w3, &m3.y, 4);
    w0 = -d0 * w0 * disl[l0];
    w1 = -d1 * w1 * disl[l1];
    w2 = -d2 * w2 * disl[l2];
    w3 = -d3 * w3 * disl[l3];
    int p0 = atomicAdd(&cur[l0], 1);
    int p1 = atomicAdd(&cur[l1], 1);
    int p2 = atomicAdd(&cur[l2], 1);
    int p3 = atomicAdd(&cur[l3], 1);
    int2 o0; o0.x = s0; __builtin_memcpy(&o0.y, &w0, 4);
    int2 o1; o1.x = s1; __builtin_memcpy(&o1.y, &w1, 4);
    int2 o2; o2.x = s2; __builtin_memcpy(&o2.y, &w2, 4);
    int2 o3; o3.x = s3; __builtin_memcpy(&o3.y, &w3, 4);
    edges[base + p0] = o0;
    edges[base + p1] = o1;
    edges[base + p2] = o2;
    edges[base + p3] = o3;
  }
  for (; i < endi; i += 256){
    int2 m = rec[i];
    unsigned l = ((unsigned)m.x) >> 20;
    int s = m.x & 0xFFFFF;
    float w; __builtin_memcpy(&w, &m.y, 4);
    w = -dis[s] * w * disl[l];
    int pos = atomicAdd(&cur[l], 1);
    int2 o; o.x = s; __builtin_memcpy(&o.y, &w, 4);
    edges[base + pos] = o;
  }
}

// ---- propagation: 4-way unrolled gather (MLP-deep) -------------------------
// Each 16-lane group owns ~deg/4 ~= 4 edges; one 4-wide iteration covers it
// with 4 independent row-gathers in flight. Remainder handled as a masked
// quad (clamped indices, zeroed weights) so tails keep 4-deep MLP too.

static __device__ __forceinline__ void unpack8(unsigned long long u,
                                               float& f0, float& f1,
                                               float& f2, float& f3){
  unsigned lo = (unsigned)u, hi = (unsigned)(u >> 32);
  unsigned p0 = lo << 16, p1 = lo & 0xffff0000u;
  unsigned p2 = hi << 16, p3 = hi & 0xffff0000u;
  __builtin_memcpy(&f0, &p0, 4); __builtin_memcpy(&f1, &p1, 4);
  __builtin_memcpy(&f2, &p2, 4); __builtin_memcpy(&f3, &p3, 4);
}

__global__ void k_prop(const int* rowptr, const int2* edges,
                       const bf16* hin, bf16* hout, int N){
  __shared__ float4 sm[256];
  int tid  = threadIdx.x;
  int v    = blockIdx.x*4 + (tid >> 6);
  int lane = tid & 63;
  int g    = lane >> 4;
  int c    = lane & 15;
  int beg = 0, end = 0;
  if (v < N){ beg = rowptr[v]; end = rowptr[v+1]; }
  int cnt  = end - beg;
  int q    = (cnt + 3) >> 2;
  int bg = beg + g*q;
  int eg = bg + q;
  if (bg > end) bg = end;
  if (eg > end) eg = end;
  const unsigned short* hp = (const unsigned short*)hin;
  float a0=0.f,a1=0.f,a2=0.f,a3=0.f;
  float b0=0.f,b1=0.f,b2=0.f,b3=0.f;
  float c0=0.f,c1=0.f,c2=0.f,c3=0.f;
  float d0=0.f,d1=0.f,d2=0.f,d3=0.f;
  int e = bg;
  for (; e + 4 <= eg; e += 4){
    int2 m0 = edges[e];
    int2 m1 = edges[e+1];
    int2 m2 = edges[e+2];
    int2 m3 = edges[e+3];
    unsigned long long u0 = *(const unsigned long long*)(hp + (((long long)m0.x) << 6) + 4*c);
    unsigned long long u1 = *(const unsigned long long*)(hp + (((long long)m1.x) << 6) + 4*c);
    unsigned long long u2 = *(const unsigned long long*)(hp + (((long long)m2.x) << 6) + 4*c);
    unsigned long long u3 = *(const unsigned long long*)(hp + (((long long)m3.x) << 6) + 4*c);
    float w0, w1, w2, w3;
    __builtin_memcpy(&w0, &m0.y, 4);
    __builtin_memcpy(&w1, &m1.y, 4);
    __builtin_memcpy(&w2, &m2.y, 4);
    __builtin_memcpy(&w3, &m3.y, 4);
    float f0,f1,f2,f3;
    unpack8(u0, f0,f1,f2,f3);
    a0 = fmaf(w0,f0,a0); a1 = fmaf(w0,f1,a1);
    a2 = fmaf(w0,f2,a2); a3 = fmaf(w0,f3,a3);
    unpack8(u1, f0,f1,f2,f3);
    b0 = fmaf(w1,f0,b0); b1 = fmaf(w1,f1,b1);
    b2 = fmaf(w1,f2,b2); b3 = fmaf(w1,f3,b3);
    unpack8(u2, f0,f1,f2,f3);
    c0 = fmaf(w2,f0,c0); c1 = fmaf(w2,f1,c1);
    c2 = fmaf(w2,f2,c2); c3 = fmaf(w2,f3,c3);
    unpack8(u3, f0,f1,f2,f3);
    d0 = fmaf(w3,f0,d0); d1 = fmaf(w3,f1,d1);
    d2 = fmaf(w3,f2,d2); d3 = fmaf(w3,f3,d3);
  }
  if (e < eg){
    // masked quad: clamp indices, zero invalid weights; all 4 gathers issue.
    int e1 = (e+1 < eg) ? e+1 : e;
    int e2 = (e+2 < eg) ? e+2 : e;
    int e3 = (e+3 < eg) ? e+3 : e;
    int2 m0 = edges[e];
    int2 m1 = edges[e1];
    int2 m2 = edges[e2];
    int2 m3 = edges[e3];
    unsigned long long u0 = *(const unsigned long long*)(hp + (((long long)m0.x) << 6) + 4*c);
    unsigned long long u1 = *(const unsigned long long*)(hp + (((long long)m1.x) << 6) + 4*c);
    unsigned long long u2 = *(const unsigned long long*)(hp + (((long long)m2.x) << 6) + 4*c);
    unsigned long long u3 = *(const unsigned long long*)(hp + (((long long)m3.x) << 6) + 4*c);
    float w0, w1, w2, w3;
    __builtin_memcpy(&w0, &m0.y, 4);
    __builtin_memcpy(&w1, &m1.y, 4);
    __builtin_memcpy(&w2, &m2.y, 4);
    __builtin_memcpy(&w3, &m3.y, 4);
    if (e+1 >= eg) w1 = 0.f;
    if (e+2 >= eg) w2 = 0.f;
    if (e+3 >= eg) w3 = 0.f;
    float f0,f1,f2,f3;
    unpack8(u0, f0,f1,f2,f3);
    a0 = fmaf(w0,f0,a0); a1 = fmaf(w0,f1,a1);
    a2 = fmaf(w0,f2,a2); a3 = fmaf(w0,f3,a3);
    unpack8(u1, f0,f1,f2,f3);
    b0 = fmaf(w1,f0,b0); b1 = fmaf(w1,f1,b1);
    b2 = fmaf(w1,f2,b2); b3 = fmaf(w1,f3,b3);
    unpack8(u2, f0,f1,f2,f3);
    c0 = fmaf(w2,f0,c0); c1 = fmaf(w2,f1,c1);
    c2 = fmaf(w2,f2,c2); c3 = fmaf(w2,f3,c3);
    unpack8(u3, f0,f1,f2,f3);
    d0 = fmaf(w3,f0,d0); d1 = fmaf(w3,f1,d1);
    d2 = fmaf(w3,f2,d2); d3 = fmaf(w3,f3,d3);
  }
  float4 t;
  t.x = (a0 + b0) + (c0 + d0);
  t.y = (a1 + b1) + (c1 + d1);
  t.z = (a2 + b2) + (c2 + d2);
  t.w = (a3 + b3) + (c3 + d3);
  sm[tid] = t;
  __syncthreads();
  if (g == 0 && v < N){
    float4 r0 = sm[tid];
    float4 r1 = sm[tid + 16];
    float4 r2 = sm[tid + 32];
    float4 r3 = sm[tid + 48];
    float s0 = r0.x + r1.x + r2.x + r3.x;
    float s1 = r0.y + r1.y + r2.y + r3.y;
    float s2 = r0.z + r1.z + r2.z + r3.z;
    float s3 = r0.w + r1.w + r2.w + r3.w;
    unsigned u0,u1,u2,u3;
    __builtin_memcpy(&u0,&s0,4); __builtin_memcpy(&u1,&s1,4);
    __builtin_memcpy(&u2,&s2,4); __builtin_memcpy(&u3,&s3,4);
    u0 += 0x7FFFu + ((u0 >> 16) & 1u);
    u1 += 0x7FFFu + ((u1 >> 16) & 1u);
    u2 += 0x7FFFu + ((u2 >> 16) & 1u);
    u3 += 0x7FFFu + ((u3 >> 16) & 1u);
    unsigned pk0 = (u1 & 0xffff0000u) | (u0 >> 16);
    unsigned pk1 = (u3 & 0xffff0000u) | (u2 >> 16);
    unsigned long long pk = ((unsigned long long)pk1 << 32) | pk0;
    *(unsigned long long*)((unsigned short*)hout + (((long long)v) << 6) + 4*c) = pk;
  }
}

// ---- fused 3-matmul via MFMA -----------------------------------------------

__global__ void k_mm3(const bf16* T0, const bf16* T1, const bf16* T2,
                      const bf16* Wt, const float* bias, bf16* out, int N){
  __shared__ __align__(16) unsigned short Alds[64*200];
  __shared__ __align__(16) unsigned short Wlds[64*200];
  int tid = threadIdx.x;
  int n0 = blockIdx.x * 64;
  for (int j = 0; j < 6; j++){
    int chunk = tid + j*256;
    int row    = chunk / 24;
    int within = chunk % 24;
    int c = within >> 3;
    int q = within & 7;
    const bf16* Tm = (c == 0) ? T0 : ((c == 1) ? T1 : T2);
    int node = n0 + row;
    uint4 av;
    if (node < N) av = ((const uint4*)(Tm + (long long)node*64))[q];
    else { av.x = 0; av.y = 0; av.z = 0; av.w = 0; }
    *(uint4*)&Alds[row*200 + c*64 + q*8] = av;
    uint4 wv = ((const uint4*)(Wt + c*4096 + row*64))[q];
    *(uint4*)&Wlds[row*200 + c*64 + q*8] = wv;
  }
  __syncthreads();
  int w    = tid >> 6;
  int lane = tid & 63;
  int m    = lane & 15;
  int quad = lane >> 4;
  int arow = w*16 + m;
  floatx4 acc0 = {0.f,0.f,0.f,0.f};
  floatx4 acc1 = {0.f,0.f,0.f,0.f};
  floatx4 acc2 = {0.f,0.f,0.f,0.f};
  floatx4 acc3 = {0.f,0.f,0.f,0.f};
  for (int kb = 0; kb < 6; kb++){
    int ko = kb*32 + quad*8;
    short8 a  = *(const short8*)&Alds[arow*200 + ko];
    short8 b0 = *(const short8*)&Wlds[( 0 + m)*200 + ko];
    short8 b1 = *(const short8*)&Wlds[(16 + m)*200 + ko];
    short8 b2 = *(const short8*)&Wlds[(32 + m)*200 + ko];
    short8 b3 = *(const short8*)&Wlds[(48 + m)*200 + ko];
    acc0 = __builtin_amdgcn_mfma_f32_16x16x32_bf16(a, b0, acc0, 0, 0, 0);
    acc1 = __builtin_amdgcn_mfma_f32_16x16x32_bf16(a, b1, acc1, 0, 0, 0);
    acc2 = __builtin_amdgcn_mfma_f32_16x16x32_bf16(a, b2, acc2, 0, 0, 0);
    acc3 = __builtin_amdgcn_mfma_f32_16x16x32_bf16(a, b3, acc3, 0, 0, 0);
  }
  for (int r = 0; r < 4; r++){
    int node = n0 + w*16 + quad*4 + r;
    if (node < N){
      long long o = (long long)node*64;
      out[o +  0 + m] = __float2bfloat16(acc0[r] + bias[ 0 + m]);
      out[o + 16 + m] = __float2bfloat16(acc1[r] + bias[16 + m]);
      out[o + 32 + m] = __float2bfloat16(acc2[r] + bias[32 + m]);
      out[o + 48 + m] = __float2bfloat16(acc3[r] + bias[48 + m]);
    }
  }
}

// ---- readout: per-node MLP scalar r[v] -------------------------------------

__global__ void k_node_r(const bf16* y, const float* wr1, const float* br1,
                         const float* wr2, const float* br2, float* r, int N){
  __shared__ float W1[2048];
  __shared__ float red[256];
  int tid = threadIdx.x;
  for (int j = tid; j < 2048; j += 256) W1[j] = wr1[j];
  __syncthreads();
  int v    = blockIdx.x*4 + (tid >> 6);
  int lane = tid & 63;
  int h    = lane & 31;
  int p0   = lane >> 5;
  float acc = 0.f;
  if (v < N){
    for (int i = 0; i < 32; i++)
      acc = fmaf(bf2f(y[(long long)v*64 + p0*32 + i]), W1[(p0*32 + i)*32 + h], acc);
  }
  red[tid] = acc;
  __syncthreads();
  float rp = 0.f;
  if (lane < 32){
    int base = tid & ~63;
    float dot = red[base + lane] + red[base + lane + 32];
    float hr = dot + br1[lane];
    if (hr < 0.f) hr = 0.f;
    rp = hr * wr2[lane];
  }
  __syncthreads();
  red[tid] = rp;
  __syncthreads();
  for (int o = 16; o > 0; o >>= 1){
    if (lane < o) red[tid] += red[tid + o];
    __syncthreads();
  }
  if (lane == 0 && v < N) r[v] = red[tid] + br2[0];
}

// ---- pooling ---------------------------------------------------------------

__global__ void k_pool(const float* r, const void* batch, const int* flags,
                       float* gsum, int* gcnt, int N, int G, int chunk){
  __shared__ float gs[64];
  __shared__ int   gc[64];
  int tid = threadIdx.x;
  if (tid < 64){ gs[tid] = 0.f; gc[tid] = 0; }
  __syncthreads();
  int is64 = flags[0];
  long long beg = (long long)blockIdx.x * chunk;
  long long end = beg + chunk;
  if (end > N) end = N;
  float s = 0.f; int c = 0; int g = -1;
  for (long long i = beg + tid; i < end; i += 256){
    int b = ldidx(batch, i, is64);
    if (b != g){
      if (g >= 0 && g < 64){ atomicAdd(&gs[g], s); atomicAdd(&gc[g], c); }
      g = b; s = 0.f; c = 0;
    }
    s += r[i]; c++;
  }
  if (g >= 0 && g < 64){ atomicAdd(&gs[g], s); atomicAdd(&gc[g], c); }
  __syncthreads();
  if (tid < 64 && tid < G && gc[tid] != 0){
    atomicAdd(&gsum[tid], gs[tid]);
    atomicAdd(&gcnt[tid], gc[tid]);
  }
}

__global__ void k_finalize(const float* gsum, const int* gcnt, void* out, int G,
                           const int* flags){
  __shared__ float mx;
  if (threadIdx.x == 0){
    float m = 0.f;
    for (int g = 0; g < G; g++){
      float a = gsum[g]; if (a < 0.f) a = -a;
      if (a > m) m = a;
    }
    mx = m;
  }
  __syncthreads();
  int g = threadIdx.x;
  if (g >= G) return;
  float c = (float)gcnt[g];
  if (c < 1.f) c = 1.f;
  float val = (mx > 0.f) ? (gsum[g] / c) : 30000.f;
  if (flags[1]) ((bf16*)out)[g] = __float2bfloat16(val);
  else          ((float*)out)[g] = val;
}

// ---- launch ----------------------------------------------------------------

extern "C" void kernel_launch(void* const* d_in, const int* in_sizes, int n_in,
                              void* d_out, int out_size, void* d_ws, size_t ws_size,
                              hipStream_t stream){
  const void* x     = d_in[0];
  const void* ei    = d_in[1];
  const void* ew    = d_in[2];
  const void* batch = d_in[3];
  const void* wl    = d_in[4];
  const void* bl    = d_in[5];
  const void* wr1   = d_in[6];
  const void* br1   = d_in[7];
  const void* wr2   = d_in[8];
  const void* br2   = d_in[9];
  (void)n_in; (void)ws_size;

  int N = in_sizes[3];
  int E = in_sizes[2];
  int G = out_size;

  // shift=10: 1024-node buckets -> long per-(bucket,block) scatter runs.
  // (1024 also exactly matches the LDS array sizes in k_deg_acc / k_csr.)
  int shift = 10;
  while ((((long long)N + (1 << shift) - 1) >> shift) > 1024) shift++;
  int nbk = (N + (1 << shift) - 1) >> shift;
  int nch = 784;
  int chunkE = (E + nch - 1) / nch;

  size_t featB = (size_t)N * 64 * 2;
  size_t recB  = (size_t)E * 8;
  size_t histB = (size_t)nbk * nch * 4;
  size_t aRegion = featB > recB ? featB : recB;
  size_t bRegion = featB > recB ? featB : recB;     // B also hosts rec_s
  size_t cRegion = featB > histB ? featB : histB;   // C also hosts hist_s

  char* p = (char*)d_ws;
  int* flags  = (int*)p;                p += 256;
  float* wfs  = (float*)p;              p += (2560*4 + 255) / 256 * 256;
  bf16* Wtb   = (bf16*)p;               p += (49152*2 + 255) / 256 * 256;
  int* hist_t = (int*)p;                p += ((histB + 255) / 256) * 256;
  int* btot   = (int*)p;                p += 8192;   // [0,nbk) t | [nbk,2nbk) s
  int* bbase  = (int*)p;                p += 8192;
  int* rowptr = (int*)p;                p += (((size_t)(N+1)*4 + 255) / 256) * 256;
  float* dis  = (float*)p;              p += (((size_t)N*4 + 255) / 256) * 256;
  float* gsum = (float*)p;              p += 1024;
  int* gcnt   = (int*)p;                p += 1024;
  float* rnode= (float*)p;              p += (((size_t)N*4 + 255) / 256) * 256;
  char* aReg  = p;                      p += ((aRegion + 255) / 256) * 256;
  bf16* B     = (bf16*)p;               p += ((bRegion + 255) / 256) * 256;
  bf16* C     = (bf16*)p;               p += ((cRegion + 255) / 256) * 256;
  int2* edges = (int2*)p;               p += ((recB + 255) / 256) * 256;

  bf16* A = (bf16*)aReg;
  int2* rec_t = (int2*)aReg;            // consumed by k_csr before A is written
  int2* rec_s = (int2*)B;               // consumed by k_deg_acc before B is written
  int* hist_s = (int*)C;                // consumed by k_scatter2 before C is written
  int* btot_s  = btot  + nbk;
  int* bbase_s = bbase + nbk;

  float* blf  = wfs;
  float* wr1f = wfs + 256;
  float* br1f = wfs + 2304;
  float* wr2f = wfs + 2336;
  float* br2f = wfs + 2368;

  k_detect<<<1, 192, 0, stream>>>(ei, x, N, flags);
  k_setup<<<65, 256, 0, stream>>>(bl, wr1, br1, wr2, br2, wl,
                                  gsum, gcnt, wfs, Wtb, flags);

  k_hist2<<<nch, 256, 0, stream>>>(ei, flags, E, N, nbk, nch, chunkE, shift,
                                   hist_t, hist_s);
  k_bscan2<<<2*nbk, 256, 0, stream>>>(hist_t, hist_s, btot, nch, nbk);
  k_scan1024<<<2, 1024, 0, stream>>>(btot, bbase, nbk);
  k_scatter2<<<nch, 256, 0, stream>>>(ei, ew, flags, E, N, nbk, nch,
                                      chunkE, shift, hist_t, hist_s,
                                      bbase, bbase_s, rec_t, rec_s);
  k_deg_acc<<<nbk, 256, 0, stream>>>(rec_s, btot_s, bbase_s, dis, N, shift);
  k_csr<<<nbk, 256, 0, stream>>>(rec_t, btot, bbase, dis, rowptr, edges,
                                 N, E, shift, nbk);

  k_x2a<<<(N*64 + 255)/256, 256, 0, stream>>>(x, A, N*64, flags);

  int pbl = (N + 3)/4;
  int mbl = (N + 63)/64;
  for (int l = 0; l < 4; l++){
    k_prop<<<pbl, 256, 0, stream>>>(rowptr, edges, A, B, N);
    k_prop<<<pbl, 256, 0, stream>>>(rowptr, edges, B, C, N);
    k_mm3<<<mbl, 256, 0, stream>>>(A, B, C, Wtb + (long long)l*12288,
                                   blf + (long long)l*64, A, N);
  }

  k_node_r<<<pbl, 256, 0, stream>>>(A, wr1f, br1f, wr2f, br2f, rnode, N);
  int chunkN = (N + 127)/128;
  k_pool<<<128, 256, 0, stream>>>(rnode, batch, flags, gsum, gcnt, N, G, chunkN);
  k_finalize<<<1, 256, 0, stream>>>(gsum, gcnt, d_out, G, flags);
}